// Round 3
// baseline (970.990 us; speedup 1.0000x reference)
//
#include <hip/hip_runtime.h>
#include <hip/hip_bf16.h>
#include <math.h>

#define CDIV(a,b) (((a)+(b)-1)/(b))

typedef __attribute__((ext_vector_type(8))) short short8;
typedef __attribute__((ext_vector_type(4))) float f32x4;

__device__ __forceinline__ float bf2f(__hip_bfloat16 h) { return __bfloat162float(h); }
__device__ __forceinline__ __hip_bfloat16 f2bf(float f) { return __float2bfloat16(f); }

// tanh-approx GELU (max dev from exact ~3e-4; threshold is 0.15)
__device__ __forceinline__ float gelu_f(float v) {
  const float u = v * (0.7978845608f + 0.0356774081f * v * v);
  const float e = __expf(2.0f * u);                                // e^{2u}
  const float t = 1.0f - 2.0f * __builtin_amdgcn_rcpf(e + 1.0f);   // tanh(u)
  return 0.5f * v * (1.0f + t);
}

// ---------------- LayerNorm over 768, fp32 in -> bf16 out ----------------
__global__ __launch_bounds__(256) void ln_kernel(
    const float* __restrict__ in, const float* __restrict__ g,
    const float* __restrict__ b, __hip_bfloat16* __restrict__ out)
{
  __shared__ float sm1[4], sm2[4];
  const int row = blockIdx.x;
  const int tid = threadIdx.x;
  const float* p = in + (size_t)row * 768;
  float x0 = p[tid], x1 = p[tid + 256], x2 = p[tid + 512];
  float s = x0 + x1 + x2;
  #pragma unroll
  for (int off = 32; off > 0; off >>= 1) s += __shfl_down(s, off, 64);
  const int l = tid & 63, w = tid >> 6;
  if (l == 0) sm1[w] = s;
  __syncthreads();
  const float mu = (sm1[0] + sm1[1] + sm1[2] + sm1[3]) * (1.0f / 768.0f);
  const float d0 = x0 - mu, d1 = x1 - mu, d2 = x2 - mu;
  float ss = d0*d0 + d1*d1 + d2*d2;
  #pragma unroll
  for (int off = 32; off > 0; off >>= 1) ss += __shfl_down(ss, off, 64);
  if (l == 0) sm2[w] = ss;
  __syncthreads();
  const float var = (sm2[0] + sm2[1] + sm2[2] + sm2[3]) * (1.0f / 768.0f);
  const float rstd = rsqrtf(var + 1e-6f);
  __hip_bfloat16* q = out + (size_t)row * 768;
  q[tid]       = f2bf(d0 * rstd * g[tid]       + b[tid]);
  q[tid + 256] = f2bf(d1 * rstd * g[tid + 256] + b[tid + 256]);
  q[tid + 512] = f2bf(d2 * rstd * g[tid + 512] + b[tid + 512]);
}

// ---------------- criss-cross attention core, 2 kf per thread ----------------
__global__ __launch_bounds__(256) void attn_kernel(
    const __hip_bfloat162* __restrict__ qkv, __hip_bfloat162* __restrict__ ctx)
{
  const long t = (long)blockIdx.x * 256 + threadIdx.x;  // one per (row, kf-pair)
  const long row = t >> 7;
  const int kp = (int)(t & 127);                        // pair index 0..127
  const __hip_bfloat162* p = qkv + row * 1152;          // 2304 bf16 = 1152 pairs
  float q[3][2], k[3][2], v[3][2];
  #pragma unroll
  for (int c = 0; c < 3; ++c) {
    __hip_bfloat162 qq = p[c*384 + kp];
    __hip_bfloat162 kk = p[c*384 + 128 + kp];
    __hip_bfloat162 vv = p[c*384 + 256 + kp];
    q[c][0] = __low2float(qq); q[c][1] = __high2float(qq);
    k[c][0] = __low2float(kk); k[c][1] = __high2float(kk);
    v[c][0] = __low2float(vv); v[c][1] = __high2float(vv);
  }
  float o[3][2] = {};
  #pragma unroll
  for (int u = 0; u < 2; ++u) {
    #pragma unroll
    for (int c = 0; c < 3; ++c) {
      const float s0 = q[c][u]*k[0][u]*0.0625f, s1 = q[c][u]*k[1][u]*0.0625f, s2 = q[c][u]*k[2][u]*0.0625f;
      const float m = fmaxf(s0, fmaxf(s1, s2));
      const float e0 = __expf(s0-m), e1 = __expf(s1-m), e2 = __expf(s2-m);
      const float inv = v[c][u] / (e0 + e1 + e2);
      o[0][u] += e0*inv; o[1][u] += e1*inv; o[2][u] += e2*inv;
    }
  }
  __hip_bfloat162* po = ctx + row * 384;
  #pragma unroll
  for (int d = 0; d < 3; ++d)
    po[d*128 + kp] = __hip_bfloat162{f2bf(o[d][0]), f2bf(o[d][1])};
}

// ---------------- LDS-tiled fp32 [K,N] -> bf16 [N,K] transpose ----------------
__global__ __launch_bounds__(256) void transpose_bf16_kernel(
    const float* __restrict__ in, __hip_bfloat16* __restrict__ out, int K, int N)
{
  __shared__ float tile[32][33];
  in  += (size_t)blockIdx.z * K * N;
  out += (size_t)blockIdx.z * K * N;
  const int n0 = blockIdx.x * 32;
  const int k0 = blockIdx.y * 32;
  const int tx = threadIdx.x & 31, ty = threadIdx.x >> 5;   // 32 x 8
  #pragma unroll
  for (int r = 0; r < 32; r += 8)
    tile[ty + r][tx] = in[(size_t)(k0 + ty + r) * N + n0 + tx];
  __syncthreads();
  #pragma unroll
  for (int r = 0; r < 32; r += 8)
    out[(size_t)(n0 + ty + r) * K + k0 + tx] = f2bf(tile[tx][ty + r]);
}

// ---------------- bf16 MFMA GEMM, B^T input, BK=32, XOR-swizzled LDS ----------------
// Grid: blockIdx.x = M-tile (fastest -> resident blocks share one B-tile),
//       blockIdx.y = N-tile, blockIdx.z = batch.
// LDS: 16B chunk q (k-bytes [16q,16q+16)) of row r stored at r*64 + 16*(q ^ (r&3)).
//   Fragment read (16 lanes/quad, rows 0..15) spans 1024B over the 512B bank
//   period with all slots distinct -> exactly 2-way aliasing = conflict-free.
// MODE 0: Cb = bf16(acc + bias[n])                 (QKV)
// MODE 1: Cf = acc + bias[n] + res[idx]            (fc_out -> xr)
// MODE 2: Cb = bf16(gelu(acc + bias[n]))           (MLP1)
// MODE 3: Cf = acc + bias[n] + res[idx]            (MLP2 -> out)
#define BM 128
#define BN 128
#define BK 32

template<int MODE>
__global__ __launch_bounds__(256) void gemm_bt_kernel(
    const __hip_bfloat16* __restrict__ A, int lda, long strideA,
    const __hip_bfloat16* __restrict__ Bt, int ldb, long strideB,
    float* __restrict__ Cf, __hip_bfloat16* __restrict__ Cb, int ldc, long strideC,
    const float* __restrict__ bias, long strideBias,
    const float* __restrict__ res,
    int K)
{
  __shared__ __align__(16) __hip_bfloat16 sA[BM * BK];   // 8 KB
  __shared__ __align__(16) __hip_bfloat16 sB[BN * BK];   // 8 KB

  const int z = blockIdx.z;
  A    += (size_t)z * strideA;
  Bt   += (size_t)z * strideB;
  bias += (size_t)z * strideBias;
  const long cOff = (long)z * strideC;

  const long tileM = (long)blockIdx.x * BM;   // M fastest
  const int  tileN = blockIdx.y * BN;

  const int tid  = threadIdx.x;
  const int lane = tid & 63;
  const int wv   = tid >> 6;
  const int waveM = (wv & 1) * 64;
  const int waveN = (wv >> 1) * 64;

  // staging: thread t loads 16B; LDS dest = hh*4096 + t*16 (wave-uniform + lane*16)
  const int srow  = tid >> 2;                         // 0..63
  const int selem = ((tid & 3) ^ (srow & 3)) * 8;     // swizzled source k-element
  // fragment coords
  const int frow = lane & 15;
  const int fq16 = (lane >> 4) << 4;                  // quad byte offset
  const int fkb  = (fq16 ^ ((frow & 3) << 4));        // swizzled byte offset in 64B row

  f32x4 acc[4][4] = {};

  char* const sAb = (char*)sA;
  char* const sBb = (char*)sB;

  for (int k0 = 0; k0 < K; k0 += BK) {
    #pragma unroll
    for (int hh = 0; hh < 2; ++hh) {
      const int r = hh * 64 + srow;
      const __hip_bfloat16* ga = A  + (tileM + r) * (size_t)lda + k0 + selem;
      const __hip_bfloat16* gb = Bt + ((long)tileN + r) * (size_t)ldb + k0 + selem;
      __builtin_amdgcn_global_load_lds(
          (const __attribute__((address_space(1))) void*)ga,
          (__attribute__((address_space(3))) void*)(sAb + hh*4096 + tid*16),
          16, 0, 0);
      __builtin_amdgcn_global_load_lds(
          (const __attribute__((address_space(1))) void*)gb,
          (__attribute__((address_space(3))) void*)(sBb + hh*4096 + tid*16),
          16, 0, 0);
    }
    __syncthreads();   // drains vmcnt -> LDS tiles complete

    short8 aF[4], bF[4];
    #pragma unroll
    for (int i = 0; i < 4; ++i)
      aF[i] = *(const short8*)(sAb + (waveM + i*16 + frow) * 64 + fkb);
    #pragma unroll
    for (int j = 0; j < 4; ++j)
      bF[j] = *(const short8*)(sBb + (waveN + j*16 + frow) * 64 + fkb);
    #pragma unroll
    for (int i = 0; i < 4; ++i)
      #pragma unroll
      for (int j = 0; j < 4; ++j)
        acc[i][j] = __builtin_amdgcn_mfma_f32_16x16x32_bf16(aF[i], bF[j], acc[i][j], 0, 0, 0);
    __syncthreads();   // protect LDS from next iteration's staging
  }

  // epilogue: C/D layout col=lane&15, row=(lane>>4)*4+reg
  #pragma unroll
  for (int i = 0; i < 4; ++i) {
    const long row0 = tileM + waveM + i*16 + ((lane >> 4) * 4);
    #pragma unroll
    for (int j = 0; j < 4; ++j) {
      const int col = tileN + waveN + j*16 + (lane & 15);
      const float bv = bias[col];
      #pragma unroll
      for (int r = 0; r < 4; ++r) {
        const long idx = cOff + (row0 + r) * (long)ldc + col;
        const float v = acc[i][j][r] + bv;
        if (MODE == 0) {
          Cb[idx] = f2bf(v);
        } else if (MODE == 1 || MODE == 3) {
          Cf[idx] = v + res[idx];
        } else {
          Cb[idx] = f2bf(gelu_f(v));
        }
      }
    }
  }
}

extern "C" void kernel_launch(void* const* d_in, const int* in_sizes, int n_in,
                              void* d_out, int out_size, void* d_ws, size_t ws_size,
                              hipStream_t stream)
{
  const float* x     = (const float*)d_in[0];
  const float* W_qkv = (const float*)d_in[1];
  const float* b_qkv = (const float*)d_in[2];
  const float* W_out = (const float*)d_in[3];
  const float* b_out = (const float*)d_in[4];
  const float* ln1_g = (const float*)d_in[5];
  const float* ln1_b = (const float*)d_in[6];
  const float* ln2_g = (const float*)d_in[7];
  const float* ln2_b = (const float*)d_in[8];
  const float* W1    = (const float*)d_in[9];
  const float* b1    = (const float*)d_in[10];
  const float* W2    = (const float*)d_in[11];
  const float* b2    = (const float*)d_in[12];
  float* out = (float*)d_out;   // holds xr after fc_out, final result after MLP2

  // workspace layout (bytes); region [0,192MB) is overlaid phase-by-phase
  char* ws = (char*)d_ws;
  __hip_bfloat16* h     = (__hip_bfloat16*)(ws + 0);           // 48 MB   (LN1 -> QKV)
  __hip_bfloat16* qkv   = (__hip_bfloat16*)(ws + 50331648);    // 144 MB  (QKV -> attn)
  __hip_bfloat16* ctx   = (__hip_bfloat16*)(ws + 0);           // 48 MB   (attn -> fc_out), reuses h
  __hip_bfloat16* act   = (__hip_bfloat16*)(ws + 0);           // 192 MB  (MLP1 -> MLP2), reuses h+qkv
  __hip_bfloat16* yln   = (__hip_bfloat16*)(ws + 201326592);   // 48 MB   (LN2 -> MLP1)
  __hip_bfloat16* wqkvT = (__hip_bfloat16*)(ws + 251658240);   // 1.18 MB
  __hip_bfloat16* woutT = (__hip_bfloat16*)(ws + 252837888);   // 128 KB
  __hip_bfloat16* w1T   = (__hip_bfloat16*)(ws + 252968960);   // 4.5 MB
  __hip_bfloat16* w2T   = (__hip_bfloat16*)(ws + 257687552);   // 4.5 MB

  // weight prep: fp32 [K,N] -> bf16 [N,K], LDS-tiled
  transpose_bf16_kernel<<<dim3(768/32, 256/32, 3), 256, 0, stream>>>(W_qkv, wqkvT, 256, 768);
  transpose_bf16_kernel<<<dim3(256/32, 256/32, 1), 256, 0, stream>>>(W_out, woutT, 256, 256);
  transpose_bf16_kernel<<<dim3(3072/32, 768/32, 1), 256, 0, stream>>>(W1, w1T, 768, 3072);
  transpose_bf16_kernel<<<dim3(768/32, 3072/32, 1), 256, 0, stream>>>(W2, w2T, 3072, 768);

  // LN1: x -> h (bf16)
  ln_kernel<<<32768, 256, 0, stream>>>(x, ln1_g, ln1_b, h);

  // QKV: per channel c: h[:, c*256:(c+1)*256] @ W_qkv[c] + b_qkv[c] -> qkv[:, c, :]
  gemm_bt_kernel<0><<<dim3(32768/BM, 768/BN, 3), 256, 0, stream>>>(
      h, 768, 256, wqkvT, 256, 768*256, nullptr, qkv, 2304, 768, b_qkv, 768, nullptr, 256);

  // per-(row,kf) 3x3 softmax attention -> ctx
  attn_kernel<<<16384, 256, 0, stream>>>((const __hip_bfloat162*)qkv, (__hip_bfloat162*)ctx);

  // fc_out: ctx[98304,256] @ W_out + b_out + x -> xr (fp32, into d_out)
  gemm_bt_kernel<1><<<dim3(98304/BM, 256/BN, 1), 256, 0, stream>>>(
      ctx, 256, 0, woutT, 256, 0, out, nullptr, 256, 0, b_out, 0, x, 256);

  // LN2: xr -> yln (bf16)
  ln_kernel<<<32768, 256, 0, stream>>>(out, ln2_g, ln2_b, yln);

  // MLP1: yln @ W1 + b1, GELU -> act (bf16)
  gemm_bt_kernel<2><<<dim3(32768/BM, 3072/BN, 1), 256, 0, stream>>>(
      yln, 768, 0, w1T, 768, 0, nullptr, act, 3072, 0, b1, 0, nullptr, 768);

  // MLP2: act @ W2 + b2 + xr -> out (fp32, in-place residual read)
  gemm_bt_kernel<3><<<dim3(32768/BM, 768/BN, 1), 256, 0, stream>>>(
      act, 3072, 0, w2T, 3072, 0, out, nullptr, 768, 0, b2, 0, out, 3072);
}

// Round 4
// 888.999 us; speedup vs baseline: 1.0922x; 1.0922x over previous
//
#include <hip/hip_runtime.h>
#include <hip/hip_bf16.h>
#include <math.h>

#define CDIV(a,b) (((a)+(b)-1)/(b))

typedef __attribute__((ext_vector_type(8))) short short8;
typedef __attribute__((ext_vector_type(4))) float f32x4;

__device__ __forceinline__ float bf2f(__hip_bfloat16 h) { return __bfloat162float(h); }
__device__ __forceinline__ __hip_bfloat16 f2bf(float f) { return __float2bfloat16(f); }

// tanh-approx GELU (max dev from exact ~3e-4; threshold is 0.15)
__device__ __forceinline__ float gelu_f(float v) {
  const float u = v * (0.7978845608f + 0.0356774081f * v * v);
  const float e = __expf(2.0f * u);                                // e^{2u}
  const float t = 1.0f - 2.0f * __builtin_amdgcn_rcpf(e + 1.0f);   // tanh(u)
  return 0.5f * v * (1.0f + t);
}

// ---------------- LayerNorm over 768, fp32 in -> bf16 out ----------------
__global__ __launch_bounds__(256) void ln_kernel(
    const float* __restrict__ in, const float* __restrict__ g,
    const float* __restrict__ b, __hip_bfloat16* __restrict__ out)
{
  __shared__ float sm1[4], sm2[4];
  const int row = blockIdx.x;
  const int tid = threadIdx.x;
  const float* p = in + (size_t)row * 768;
  float x0 = p[tid], x1 = p[tid + 256], x2 = p[tid + 512];
  float s = x0 + x1 + x2;
  #pragma unroll
  for (int off = 32; off > 0; off >>= 1) s += __shfl_down(s, off, 64);
  const int l = tid & 63, w = tid >> 6;
  if (l == 0) sm1[w] = s;
  __syncthreads();
  const float mu = (sm1[0] + sm1[1] + sm1[2] + sm1[3]) * (1.0f / 768.0f);
  const float d0 = x0 - mu, d1 = x1 - mu, d2 = x2 - mu;
  float ss = d0*d0 + d1*d1 + d2*d2;
  #pragma unroll
  for (int off = 32; off > 0; off >>= 1) ss += __shfl_down(ss, off, 64);
  if (l == 0) sm2[w] = ss;
  __syncthreads();
  const float var = (sm2[0] + sm2[1] + sm2[2] + sm2[3]) * (1.0f / 768.0f);
  const float rstd = rsqrtf(var + 1e-6f);
  __hip_bfloat16* q = out + (size_t)row * 768;
  q[tid]       = f2bf(d0 * rstd * g[tid]       + b[tid]);
  q[tid + 256] = f2bf(d1 * rstd * g[tid + 256] + b[tid + 256]);
  q[tid + 512] = f2bf(d2 * rstd * g[tid + 512] + b[tid + 512]);
}

// ---------------- criss-cross attention core, 2 kf per thread ----------------
__global__ __launch_bounds__(256) void attn_kernel(
    const __hip_bfloat162* __restrict__ qkv, __hip_bfloat162* __restrict__ ctx)
{
  const long t = (long)blockIdx.x * 256 + threadIdx.x;  // one per (row, kf-pair)
  const long row = t >> 7;
  const int kp = (int)(t & 127);                        // pair index 0..127
  const __hip_bfloat162* p = qkv + row * 1152;          // 2304 bf16 = 1152 pairs
  float q[3][2], k[3][2], v[3][2];
  #pragma unroll
  for (int c = 0; c < 3; ++c) {
    __hip_bfloat162 qq = p[c*384 + kp];
    __hip_bfloat162 kk = p[c*384 + 128 + kp];
    __hip_bfloat162 vv = p[c*384 + 256 + kp];
    q[c][0] = __low2float(qq); q[c][1] = __high2float(qq);
    k[c][0] = __low2float(kk); k[c][1] = __high2float(kk);
    v[c][0] = __low2float(vv); v[c][1] = __high2float(vv);
  }
  float o[3][2] = {};
  #pragma unroll
  for (int u = 0; u < 2; ++u) {
    #pragma unroll
    for (int c = 0; c < 3; ++c) {
      const float s0 = q[c][u]*k[0][u]*0.0625f, s1 = q[c][u]*k[1][u]*0.0625f, s2 = q[c][u]*k[2][u]*0.0625f;
      const float m = fmaxf(s0, fmaxf(s1, s2));
      const float e0 = __expf(s0-m), e1 = __expf(s1-m), e2 = __expf(s2-m);
      const float inv = v[c][u] / (e0 + e1 + e2);
      o[0][u] += e0*inv; o[1][u] += e1*inv; o[2][u] += e2*inv;
    }
  }
  __hip_bfloat162* po = ctx + row * 384;
  #pragma unroll
  for (int d = 0; d < 3; ++d)
    po[d*128 + kp] = __hip_bfloat162{f2bf(o[d][0]), f2bf(o[d][1])};
}

// ---------------- LDS-tiled fp32 [K,N] -> bf16 [N,K] transpose ----------------
__global__ __launch_bounds__(256) void transpose_bf16_kernel(
    const float* __restrict__ in, __hip_bfloat16* __restrict__ out, int K, int N)
{
  __shared__ float tile[32][33];
  in  += (size_t)blockIdx.z * K * N;
  out += (size_t)blockIdx.z * K * N;
  const int n0 = blockIdx.x * 32;
  const int k0 = blockIdx.y * 32;
  const int tx = threadIdx.x & 31, ty = threadIdx.x >> 5;   // 32 x 8
  #pragma unroll
  for (int r = 0; r < 32; r += 8)
    tile[ty + r][tx] = in[(size_t)(k0 + ty + r) * N + n0 + tx];
  __syncthreads();
  #pragma unroll
  for (int r = 0; r < 32; r += 8)
    out[(size_t)(n0 + ty + r) * K + k0 + tx] = f2bf(tile[tx][ty + r]);
}

// ---------------- bf16 MFMA GEMM, B^T input, BK=32, dbuf-pipelined ----------------
// Grid: blockIdx.x = M-tile (fastest -> resident blocks share one B-tile),
//       blockIdx.y = N-tile, blockIdx.z = batch.
// LDS swizzle (64-B rows): chunk c (k-bytes [16c,16c+16)) of row r stored at
//   r*64 + 16*(c ^ ((r>>1)&3)).  Granule index mod 8 = 4*(r&1) + c^((r>>1)&3):
//   over any 8 consecutive rows at fixed chunk this is a permutation of 0..7
//   -> every 8-lane ds_read_b128 phase hits 8 distinct granules = conflict-free.
// K-loop: two LDS buffers; stage(t+1) issued before waiting on tile t with
//   s_waitcnt vmcnt(4) (4 loads/thread/tile stay in flight across the barrier).
// MODE 0: Cb = bf16(acc + bias[n])                 (QKV)
// MODE 1: Cf = acc + bias[n] + res[idx]            (fc_out -> xr)
// MODE 2: Cb = bf16(gelu(acc + bias[n]))           (MLP1)
// MODE 3: Cf = acc + bias[n] + res[idx]            (MLP2 -> out)
#define BM 128
#define BN 128
#define BK 32

template<int MODE>
__global__ __launch_bounds__(256) void gemm_bt_kernel(
    const __hip_bfloat16* __restrict__ A, int lda, long strideA,
    const __hip_bfloat16* __restrict__ Bt, int ldb, long strideB,
    float* __restrict__ Cf, __hip_bfloat16* __restrict__ Cb, int ldc, long strideC,
    const float* __restrict__ bias, long strideBias,
    const float* __restrict__ res,
    int K)
{
  __shared__ __align__(16) char sAll[2 * 16384];   // 2 x (sA 8KB + sB 8KB)

  const int z = blockIdx.z;
  A    += (size_t)z * strideA;
  Bt   += (size_t)z * strideB;
  bias += (size_t)z * strideBias;
  const long cOff = (long)z * strideC;

  const long tileM = (long)blockIdx.x * BM;   // M fastest
  const int  tileN = blockIdx.y * BN;

  const int tid  = threadIdx.x;
  const int lane = tid & 63;
  const int wv   = tid >> 6;
  const int waveM = (wv & 1) * 64;
  const int waveN = (wv >> 1) * 64;

  // staging: thread t covers row srow, LDS chunk (tid&3); source k-chunk is
  // XOR-swizzled. LDS dest = buf + [0|8192] + hh*4096 + tid*16 (uniform+lane*16).
  const int srow  = tid >> 2;                          // 0..63
  const int selem = ((tid & 3) ^ ((srow >> 1) & 3)) * 8;
  // fragment coords
  const int frow = lane & 15;
  const int fkb  = (((lane >> 4) ^ ((frow >> 1) & 3)) << 4);  // swizzled byte offs

  const __hip_bfloat16* Ab = A  + tileM * (size_t)lda + selem;
  const __hip_bfloat16* Bb = Bt + (long)tileN * (size_t)ldb + selem;

  f32x4 acc[4][4] = {};

  const int T = K / BK;

  // ---- stage tile 0 into buffer 0 ----
  {
    #pragma unroll
    for (int hh = 0; hh < 2; ++hh) {
      const int r = hh * 64 + srow;
      __builtin_amdgcn_global_load_lds(
          (const __attribute__((address_space(1))) void*)(Ab + (size_t)r * lda),
          (__attribute__((address_space(3))) void*)(sAll + hh*4096 + tid*16), 16, 0, 0);
      __builtin_amdgcn_global_load_lds(
          (const __attribute__((address_space(1))) void*)(Bb + (size_t)r * ldb),
          (__attribute__((address_space(3))) void*)(sAll + 8192 + hh*4096 + tid*16), 16, 0, 0);
    }
  }

  for (int t = 0; t < T; ++t) {
    const int buf = (t & 1) * 16384;
    if (t + 1 < T) {
      const int nbuf = 16384 - buf;
      const int k0 = (t + 1) * BK;
      #pragma unroll
      for (int hh = 0; hh < 2; ++hh) {
        const int r = hh * 64 + srow;
        __builtin_amdgcn_global_load_lds(
            (const __attribute__((address_space(1))) void*)(Ab + (size_t)r * lda + k0),
            (__attribute__((address_space(3))) void*)(sAll + nbuf + hh*4096 + tid*16), 16, 0, 0);
        __builtin_amdgcn_global_load_lds(
            (const __attribute__((address_space(1))) void*)(Bb + (size_t)r * ldb + k0),
            (__attribute__((address_space(3))) void*)(sAll + nbuf + 8192 + hh*4096 + tid*16), 16, 0, 0);
      }
      asm volatile("s_waitcnt vmcnt(4)" ::: "memory");   // drain tile t only
    } else {
      asm volatile("s_waitcnt vmcnt(0)" ::: "memory");
    }
    __builtin_amdgcn_s_barrier();                        // buf[t] published

    const char* sAb = sAll + buf;
    const char* sBb = sAb + 8192;
    short8 aF[4], bF[4];
    #pragma unroll
    for (int i = 0; i < 4; ++i)
      aF[i] = *(const short8*)(sAb + (waveM + i*16 + frow) * 64 + fkb);
    #pragma unroll
    for (int j = 0; j < 4; ++j)
      bF[j] = *(const short8*)(sBb + (waveN + j*16 + frow) * 64 + fkb);
    #pragma unroll
    for (int i = 0; i < 4; ++i)
      #pragma unroll
      for (int j = 0; j < 4; ++j)
        acc[i][j] = __builtin_amdgcn_mfma_f32_16x16x32_bf16(aF[i], bF[j], acc[i][j], 0, 0, 0);

    __builtin_amdgcn_s_barrier();                        // readers of buf[t] done
  }

  // epilogue: C/D layout col=lane&15, row=(lane>>4)*4+reg
  #pragma unroll
  for (int i = 0; i < 4; ++i) {
    const long row0 = tileM + waveM + i*16 + ((lane >> 4) * 4);
    #pragma unroll
    for (int j = 0; j < 4; ++j) {
      const int col = tileN + waveN + j*16 + (lane & 15);
      const float bv = bias[col];
      #pragma unroll
      for (int r = 0; r < 4; ++r) {
        const long idx = cOff + (row0 + r) * (long)ldc + col;
        const float v = acc[i][j][r] + bv;
        if (MODE == 0) {
          Cb[idx] = f2bf(v);
        } else if (MODE == 1 || MODE == 3) {
          Cf[idx] = v + res[idx];
        } else {
          Cb[idx] = f2bf(gelu_f(v));
        }
      }
    }
  }
}

extern "C" void kernel_launch(void* const* d_in, const int* in_sizes, int n_in,
                              void* d_out, int out_size, void* d_ws, size_t ws_size,
                              hipStream_t stream)
{
  const float* x     = (const float*)d_in[0];
  const float* W_qkv = (const float*)d_in[1];
  const float* b_qkv = (const float*)d_in[2];
  const float* W_out = (const float*)d_in[3];
  const float* b_out = (const float*)d_in[4];
  const float* ln1_g = (const float*)d_in[5];
  const float* ln1_b = (const float*)d_in[6];
  const float* ln2_g = (const float*)d_in[7];
  const float* ln2_b = (const float*)d_in[8];
  const float* W1    = (const float*)d_in[9];
  const float* b1    = (const float*)d_in[10];
  const float* W2    = (const float*)d_in[11];
  const float* b2    = (const float*)d_in[12];
  float* out = (float*)d_out;   // holds xr after fc_out, final result after MLP2

  // workspace layout (bytes); region [0,192MB) is overlaid phase-by-phase
  char* ws = (char*)d_ws;
  __hip_bfloat16* h     = (__hip_bfloat16*)(ws + 0);           // 48 MB   (LN1 -> QKV)
  __hip_bfloat16* qkv   = (__hip_bfloat16*)(ws + 50331648);    // 144 MB  (QKV -> attn)
  __hip_bfloat16* ctx   = (__hip_bfloat16*)(ws + 0);           // 48 MB   (attn -> fc_out), reuses h
  __hip_bfloat16* act   = (__hip_bfloat16*)(ws + 0);           // 192 MB  (MLP1 -> MLP2), reuses h+qkv
  __hip_bfloat16* yln   = (__hip_bfloat16*)(ws + 201326592);   // 48 MB   (LN2 -> MLP1)
  __hip_bfloat16* wqkvT = (__hip_bfloat16*)(ws + 251658240);   // 1.18 MB
  __hip_bfloat16* woutT = (__hip_bfloat16*)(ws + 252837888);   // 128 KB
  __hip_bfloat16* w1T   = (__hip_bfloat16*)(ws + 252968960);   // 4.5 MB
  __hip_bfloat16* w2T   = (__hip_bfloat16*)(ws + 257687552);   // 4.5 MB

  // weight prep: fp32 [K,N] -> bf16 [N,K], LDS-tiled
  transpose_bf16_kernel<<<dim3(768/32, 256/32, 3), 256, 0, stream>>>(W_qkv, wqkvT, 256, 768);
  transpose_bf16_kernel<<<dim3(256/32, 256/32, 1), 256, 0, stream>>>(W_out, woutT, 256, 256);
  transpose_bf16_kernel<<<dim3(3072/32, 768/32, 1), 256, 0, stream>>>(W1, w1T, 768, 3072);
  transpose_bf16_kernel<<<dim3(768/32, 3072/32, 1), 256, 0, stream>>>(W2, w2T, 3072, 768);

  // LN1: x -> h (bf16)
  ln_kernel<<<32768, 256, 0, stream>>>(x, ln1_g, ln1_b, h);

  // QKV: per channel c: h[:, c*256:(c+1)*256] @ W_qkv[c] + b_qkv[c] -> qkv[:, c, :]
  gemm_bt_kernel<0><<<dim3(32768/BM, 768/BN, 3), 256, 0, stream>>>(
      h, 768, 256, wqkvT, 256, 768*256, nullptr, qkv, 2304, 768, b_qkv, 768, nullptr, 256);

  // per-(row,kf) 3x3 softmax attention -> ctx
  attn_kernel<<<16384, 256, 0, stream>>>((const __hip_bfloat162*)qkv, (__hip_bfloat162*)ctx);

  // fc_out: ctx[98304,256] @ W_out + b_out + x -> xr (fp32, into d_out)
  gemm_bt_kernel<1><<<dim3(98304/BM, 256/BN, 1), 256, 0, stream>>>(
      ctx, 256, 0, woutT, 256, 0, out, nullptr, 256, 0, b_out, 0, x, 256);

  // LN2: xr -> yln (bf16)
  ln_kernel<<<32768, 256, 0, stream>>>(out, ln2_g, ln2_b, yln);

  // MLP1: yln @ W1 + b1, GELU -> act (bf16)
  gemm_bt_kernel<2><<<dim3(32768/BM, 3072/BN, 1), 256, 0, stream>>>(
      yln, 768, 0, w1T, 768, 0, nullptr, act, 3072, 0, b1, 0, nullptr, 768);

  // MLP2: act @ W2 + b2 + xr -> out (fp32, in-place residual read)
  gemm_bt_kernel<3><<<dim3(32768/BM, 768/BN, 1), 256, 0, stream>>>(
      act, 3072, 0, w2T, 3072, 0, out, nullptr, 768, 0, b2, 0, out, 3072);
}